// Round 8
// baseline (198.384 us; speedup 1.0000x reference)
//
#include <hip/hip_runtime.h>
#include <cstdint>
#include <cstddef>

// Outputs concat (f32): out(8,1024,256) qh(8,8,1024,32) kh(8,8,1024,32)
//                       v_img(8,256,32,32) atten(8,8,1024,1024)
#define OFF_OUT   0
#define OFF_QH    2097152
#define OFF_KH    4194304
#define OFF_VIMG  6291456
#define OFF_ATT   8388608

// ws layout (4-byte units)
#define WS_MQ   0        // 8*8*1024 u32
#define WS_MK   65536
#define WS_TBL  131072   // 1024*128*2 f32 (cos,sin interleaved)
#define WS_KVP  393216   // 64 bh * 4 seg * 32*32 f32 partial kv
#define WS_KMP  655360   // 64 bh * 4 seg * 32 f32 partial k-bit counts

typedef float f32x4 __attribute__((ext_vector_type(4)));

// spread low 8 bits of v to bits 0,4,8,...,28
__device__ __forceinline__ unsigned spread4(unsigned v) {
    v &= 0xFFu;
    v = (v | (v << 12)) & 0x000F000Fu;
    v = (v | (v << 6))  & 0x03030303u;
    v = (v | (v << 3))  & 0x11111111u;
    return v;
}

// ---- fused GEMM+BN+LIF+pack, LDS-free ----
// 512 thr = 8 waves; wave <-> one n (8 n per block); lane <-> 4 consecutive c
// of a 256-wide half (half=0 -> q channels/mq, half=1 -> k channels/mk).
// x[b,n,k] is wave-uniform -> scalar loads; W read as coalesced b128 from L2.
__device__ __forceinline__ void gemm_lif_512t(
    const float* __restrict__ x, const float* __restrict__ Wqk,
    const float* __restrict__ bqk, const float* __restrict__ gamma,
    const float* __restrict__ beta, unsigned* __restrict__ mq,
    unsigned* __restrict__ mk, int blk_n, int half, int t)
{
    const int lane = t & 63;
    const int wv = __builtin_amdgcn_readfirstlane(t >> 6);
    const int n = blk_n * 8 + wv;
    const int c0 = half * 256;
    const float* __restrict__ wp = Wqk + c0 + lane * 4;
    const float* __restrict__ xn = x + (size_t)n * 256;   // + b*262144 + k

    float acc[8][4];
    #pragma unroll
    for (int b = 0; b < 8; ++b)
        acc[b][0] = acc[b][1] = acc[b][2] = acc[b][3] = 0.f;

    #pragma unroll 4
    for (int k = 0; k < 256; ++k) {
        f32x4 w4 = *(const f32x4*)(wp + (size_t)k * 512);
        #pragma unroll
        for (int b = 0; b < 8; ++b) {
            float xv = xn[b * 262144 + k];                // uniform -> s_load
            acc[b][0] = fmaf(xv, w4[0], acc[b][0]);
            acc[b][1] = fmaf(xv, w4[1], acc[b][1]);
            acc[b][2] = fmaf(xv, w4[2], acc[b][2]);
            acc[b][3] = fmaf(xv, w4[3], acc[b][3]);
        }
    }

    // BN + LIF (serial over b, ascending k chain preserved) + ballot pack
    float g = gamma[n], be = beta[n];
    f32x4 bq = *(const f32x4*)(bqk + c0 + lane * 4);
    unsigned* __restrict__ dst = half ? mk : mq;
    const int hh = lane >> 3;
    float v0 = 0.f, v1 = 0.f, v2 = 0.f, v3 = 0.f;
    #pragma unroll
    for (int b = 0; b < 8; ++b) {
        float a0 = (acc[b][0] + bq[0]) * g + be;
        float a1 = (acc[b][1] + bq[1]) * g + be;
        float a2 = (acc[b][2] + bq[2]) * g + be;
        float a3 = (acc[b][3] + bq[3]) * g + be;
        v0 = v0 + (a0 - v0) * 0.5f; v1 = v1 + (a1 - v1) * 0.5f;
        v2 = v2 + (a2 - v2) * 0.5f; v3 = v3 + (a3 - v3) * 0.5f;
        bool s0 = (v0 >= 1.f), s1 = (v1 >= 1.f), s2 = (v2 >= 1.f), s3 = (v3 >= 1.f);
        v0 = s0 ? 0.f : v0; v1 = s1 ? 0.f : v1;
        v2 = s2 ? 0.f : v2; v3 = s3 ? 0.f : v3;
        unsigned long long m0 = __ballot(s0 ? 1 : 0);
        unsigned long long m1 = __ballot(s1 ? 1 : 0);
        unsigned long long m2 = __ballot(s2 ? 1 : 0);
        unsigned long long m3 = __ballot(s3 ? 1 : 0);
        if ((lane & 7) == b) {
            unsigned wd = spread4((unsigned)(m0 >> (hh * 8)))
                        | (spread4((unsigned)(m1 >> (hh * 8))) << 1)
                        | (spread4((unsigned)(m2 >> (hh * 8))) << 2)
                        | (spread4((unsigned)(m3 >> (hh * 8))) << 3);
            dst[b * 8192 + hh * 1024 + n] = wd;
        }
    }
}

// =====================================================================
// Phase A (512 thr, 1408 blocks):
//  [0,128)    : GEMM half=1 -> mk
//  [128,1152) : vimg transpose, 2 tiles/block
//  [1152,1408): rope table
// =====================================================================
__global__ __launch_bounds__(512) void phaseA_kernel(
    const float* __restrict__ x, const float* __restrict__ Wqk,
    const float* __restrict__ bqk, const float* __restrict__ gamma,
    const float* __restrict__ beta, unsigned* __restrict__ mq,
    unsigned* __restrict__ mk, float* __restrict__ vimg,
    float* __restrict__ tbl)
{
    __shared__ float smem[2112];
    int t = threadIdx.x;
    int blk = blockIdx.x;
    if (blk < 128) {
        gemm_lif_512t(x, Wqk, bqk, gamma, beta, mq, mk, blk, 1, t);
        return;
    }
    if (blk >= 1152) {                     // ---- rope table ----
        int id = (blk - 1152) * 512 + t;   // 131072 total
        int j = id & 127, n = id >> 7;
        int i = (j < 64) ? j : j - 64;
        float th = powf(10000.0f, -(float)i * (1.0f / 64.0f));
        float pos = (float)((j < 64) ? (n >> 5) : (n & 31));
        float ang = pos * th;
        tbl[n * 256 + j * 2]     = cosf(ang);
        tbl[n * 256 + j * 2 + 1] = sinf(ang);
        return;
    }
    // ---- vimg transpose ----
    int tile = (blk - 128) * 2 + (t >> 8);
    int st = t & 255;
    float* s = smem + (t >> 8) * 1056; // [32][33]
    int b = tile >> 8, ti = tile & 255;
    int p0 = (ti >> 3) * 32, c0 = (ti & 7) * 32;
    int row = st >> 3, c4 = (st & 7) * 4;
    const float4 vl = *(const float4*)&x[(b * 1024 + p0 + row) * 256 + c0 + c4];
    s[row * 33 + c4 + 0] = vl.x; s[row * 33 + c4 + 1] = vl.y;
    s[row * 33 + c4 + 2] = vl.z; s[row * 33 + c4 + 3] = vl.w;
    __syncthreads();
    int cc = st >> 3, p4 = (st & 7) * 4;
    f32x4 o;
    o.x = s[(p4 + 0) * 33 + cc]; o.y = s[(p4 + 1) * 33 + cc];
    o.z = s[(p4 + 2) * 33 + cc]; o.w = s[(p4 + 3) * 33 + cc];
    *(f32x4*)&vimg[(b * 256 + c0 + cc) * 1024 + p0 + p4] = o;
}

// =====================================================================
// Phase B (512 thr, 256 blocks):
//  [0,128)   : GEMM half=0 -> mq
//  [128,256) : kv partials + k-bit counts, 2 units/block (needs mk, tbl)
// =====================================================================
__global__ __launch_bounds__(512) void phaseB_kernel(
    const float* __restrict__ x, const float* __restrict__ Wqk,
    const float* __restrict__ bqk, const float* __restrict__ gamma,
    const float* __restrict__ beta, unsigned* __restrict__ mq,
    unsigned* __restrict__ mk, const float* __restrict__ tbl,
    float* __restrict__ kvp, float* __restrict__ kmp)
{
    __shared__ float smem[9600];
    int t = threadIdx.x;
    int blk = blockIdx.x;
    if (blk < 128) {
        gemm_lif_512t(x, Wqk, bqk, gamma, beta, mq, mk, blk, 0, t);
        return;
    }
    // ---- kv partials: 2 independent 256-thr units ----
    int ks2 = t >> 8, tl = t & 255;
    int unit = (blk - 128) * 2 + ks2;      // 0..255
    int bh = unit >> 2, seg = unit & 3;
    int b = bh >> 3, h = bh & 7;
    int n0 = seg * 256;
    float* kr   = smem + ks2 * 4800;       // [64][36]
    float* vhs  = kr + 2304;               // [64][33]
    float* part = kr + 4416;               // [8][32]
    int d = tl & 31, ch = tl >> 5;
    int sc = 0;
    for (int i = 0; i < 32; ++i)
        sc += (mk[bh * 1024 + n0 + ch * 32 + i] >> d) & 1u;
    part[ch * 32 + d] = (float)sc;
    __syncthreads();
    if (tl < 32) {
        float cs = 0.f;
        #pragma unroll
        for (int j = 0; j < 8; ++j) cs += part[j * 32 + tl];
        kmp[bh * 128 + seg * 32 + tl] = cs;
    }
    float a0 = 0, a1 = 0, a2 = 0, a3 = 0;
    int e = tl & 31, db = (tl >> 5) * 4;
    for (int c0 = n0; c0 < n0 + 256; c0 += 64) {
        __syncthreads();
        #pragma unroll
        for (int i = 0; i < 8; ++i) {
            int f = tl + i * 256;
            int nn = f >> 5, dd = f & 31;
            int n = c0 + nn;
            unsigned w = mk[bh * 1024 + n];
            float kd = 1.0f + (float)((w >> dd) & 1u);
            float ko = 1.0f + (float)((w >> (dd ^ 1)) & 1u);
            const float* cp = tbl + n * 256 + h * 32 + (dd & ~1);
            float cc2 = cp[0], ss2 = cp[1];
            kr[nn * 36 + dd] = (dd & 1) ? (ss2 * ko + cc2 * kd) : (cc2 * kd - ss2 * ko);
            vhs[nn * 33 + dd] = x[(b * 1024 + n) * 256 + h * 32 + dd];
        }
        __syncthreads();
        #pragma unroll 8
        for (int nn = 0; nn < 64; ++nn) {
            float ve = vhs[nn * 33 + e];
            float4 kk = *(const float4*)&kr[nn * 36 + db];
            a0 = fmaf(kk.x, ve, a0); a1 = fmaf(kk.y, ve, a1);
            a2 = fmaf(kk.z, ve, a2); a3 = fmaf(kk.w, ve, a3);
        }
    }
    float* dst = kvp + bh * 4096 + seg * 1024;
    dst[(db + 0) * 32 + e] = a0;
    dst[(db + 1) * 32 + e] = a1;
    dst[(db + 2) * 32 + e] = a2;
    dst[(db + 3) * 32 + e] = a3;
}

// =====================================================================
// Phase C (256 thr, 2560 blocks): all heavy writes (plain stores)
//  [0,512)    : out = q_rope@kv * z + lepe
//  [512,2560) : atten + qh/kh regen
// =====================================================================
__global__ __launch_bounds__(256) void phaseC_kernel(
    const unsigned* __restrict__ mq, const unsigned* __restrict__ mk,
    const float* __restrict__ x, const float* __restrict__ tbl,
    const float* __restrict__ kvp, const float* __restrict__ kmp,
    const float* __restrict__ lw, const float* __restrict__ lb,
    float* __restrict__ outbase)
{
    int t = threadIdx.x;
    if (blockIdx.x >= 512) {               // ---- atten + qh/kh ----
        int blk = blockIdx.x - 512;
        int bh = blk >> 5;
        int tile = blk & 31;
        float* qh = outbase + OFF_QH;
        float* kh = outbase + OFF_KH;
        float* att = outbase + OFF_ATT;
        {
            int row = tile * 32 + (t >> 3);
            int d0 = (t & 7) * 4;
            unsigned wq = mq[bh * 1024 + row], wk = mk[bh * 1024 + row];
            f32x4 a, bb;
            a.x = 1.f + (float)((wq >> (d0 + 0)) & 1u);
            a.y = 1.f + (float)((wq >> (d0 + 1)) & 1u);
            a.z = 1.f + (float)((wq >> (d0 + 2)) & 1u);
            a.w = 1.f + (float)((wq >> (d0 + 3)) & 1u);
            bb.x = 1.f + (float)((wk >> (d0 + 0)) & 1u);
            bb.y = 1.f + (float)((wk >> (d0 + 1)) & 1u);
            bb.z = 1.f + (float)((wk >> (d0 + 2)) & 1u);
            bb.w = 1.f + (float)((wk >> (d0 + 3)) & 1u);
            *(f32x4*)&qh[((bh * 1024 + row) << 5) + d0] = a;
            *(f32x4*)&kh[((bh * 1024 + row) << 5) + d0] = bb;
        }
        uint4 mm = ((const uint4*)(mk + bh * 1024))[t];
        float4 rr;
        rr.x = (float)__popc(mm.x); rr.y = (float)__popc(mm.y);
        rr.z = (float)__popc(mm.z); rr.w = (float)__popc(mm.w);
        float* base = att + ((size_t)bh * 1024 + (size_t)tile * 32) * 1024;
        const unsigned* mqrow = mq + bh * 1024 + tile * 32;
        for (int row = 0; row < 32; ++row) {
            unsigned mqw = mqrow[row];
            float rq = 32.0f + (float)__popc(mqw);
            f32x4 o;
            o.x = rq + rr.x + (float)__popc(mqw & mm.x);
            o.y = rq + rr.y + (float)__popc(mqw & mm.y);
            o.z = rq + rr.z + (float)__popc(mqw & mm.z);
            o.w = rq + rr.w + (float)__popc(mqw & mm.w);
            ((f32x4*)(base + (size_t)row * 1024))[t] = o;
        }
        return;
    }
    // ---- out ----
    int bi = blockIdx.x;
    int bh = bi >> 3, sub = bi & 7;
    int pseg = sub >> 1, half = sub & 1;
    int b = bh >> 3, h = bh & 7;
    bool hy = (h < 4);
    int e = t & 31, p_l = t >> 5;
    int p = pseg * 8 + p_l;
    int q0 = half * 16;
    float* out = outbase + OFF_OUT;

    __shared__ float kvs[32][32];
    __shared__ float kmf[32];
    __shared__ float zs[128];
    const float inv = 1.0f / 1024.0f;
    #pragma unroll
    for (int i = 0; i < 4; ++i) {
        int f = t + i * 256;
        const float* kp = kvp + bh * 4096 + f;
        kvs[f >> 5][f & 31] = (kp[0] + kp[1024] + kp[2048] + kp[3072]) * inv;
    }
    if (t < 32) {
        const float* mp = kmp + bh * 128 + t;
        kmf[t] = 1.0f + (mp[0] + mp[32] + mp[64] + mp[96]) * inv;
    }
    __syncthreads();
    float S = 0.f;
    #pragma unroll
    for (int dd = 0; dd < 32; ++dd) S += kmf[dd];
    if (t < 128) {
        int pl2 = t >> 4, iq = t & 15;
        int pp = pseg * 8 + pl2, qq = q0 + iq;
        int n = hy ? (pp * 32 + qq) : (qq * 32 + pp);
        unsigned w = mq[bh * 1024 + n];
        float acc = S;
        #pragma unroll
        for (int dd = 0; dd < 32; ++dd)
            acc += (float)((w >> dd) & 1u) * kmf[dd];
        zs[t] = 1.0f / (acc + 1e-6f);
    }
    int n_ref = hy ? (p * 32) : p;
    const float* cp = tbl + n_ref * 256 + h * 32;
    float E[16], O[16], B = 0.f;
    #pragma unroll
    for (int j = 0; j < 16; ++j) {
        float c2 = cp[2 * j], s2 = cp[2 * j + 1];
        float K0 = kvs[2 * j][e], K1 = kvs[2 * j + 1][e];
        E[j] = c2 * K0 + s2 * K1;
        O[j] = c2 * K1 - s2 * K0;
        B += E[j] + O[j];
    }
    __syncthreads();
    int c = h * 32 + e;
    float w9[9];
    #pragma unroll
    for (int j = 0; j < 9; ++j) w9[j] = lw[c * 9 + j];
    float lbv = lb[c];
    const float* xb = x + (size_t)b * 262144 + c;
    auto ld = [&](int yy, int xx) -> float {
        if ((unsigned)yy > 31u || (unsigned)xx > 31u) return 0.f;
        return xb[(yy * 32 + xx) * 256];
    };
    if (hy) {
        int y = p;
        float Wm0 = ld(y - 1, q0 - 1), Wm1 = ld(y, q0 - 1), Wm2 = ld(y + 1, q0 - 1);
        float Wc0 = ld(y - 1, q0),     Wc1 = ld(y, q0),     Wc2 = ld(y + 1, q0);
        #pragma unroll 4
        for (int i = 0; i < 16; ++i) {
            int m = q0 + i;
            float Wp0 = ld(y - 1, m + 1), Wp1 = ld(y, m + 1), Wp2 = ld(y + 1, m + 1);
            int n = y * 32 + m;
            unsigned w = mq[bh * 1024 + n];
            float o = B;
            #pragma unroll
            for (int j = 0; j < 16; ++j) {
                o += (float)((w >> (2 * j)) & 1u) * E[j];
                o += (float)((w >> (2 * j + 1)) & 1u) * O[j];
            }
            o *= zs[p_l * 16 + i];
            float l = lbv;
            l = fmaf(w9[0], Wm0, l); l = fmaf(w9[1], Wc0, l); l = fmaf(w9[2], Wp0, l);
            l = fmaf(w9[3], Wm1, l); l = fmaf(w9[4], Wc1, l); l = fmaf(w9[5], Wp1, l);
            l = fmaf(w9[6], Wm2, l); l = fmaf(w9[7], Wc2, l); l = fmaf(w9[8], Wp2, l);
            out[((b * 1024 + n) << 8) + c] = o + l;
            Wm0 = Wc0; Wm1 = Wc1; Wm2 = Wc2;
            Wc0 = Wp0; Wc1 = Wp1; Wc2 = Wp2;
        }
    } else {
        int xx0 = p;
        float Wm0 = ld(q0 - 1, xx0 - 1), Wm1 = ld(q0 - 1, xx0), Wm2 = ld(q0 - 1, xx0 + 1);
        float Wc0 = ld(q0, xx0 - 1),     Wc1 = ld(q0, xx0),     Wc2 = ld(q0, xx0 + 1);
        #pragma unroll 4
        for (int i = 0; i < 16; ++i) {
            int m = q0 + i;
            float Wp0 = ld(m + 1, xx0 - 1), Wp1 = ld(m + 1, xx0), Wp2 = ld(m + 1, xx0 + 1);
            int n = m * 32 + xx0;
            unsigned w = mq[bh * 1024 + n];
            float o = B;
            #pragma unroll
            for (int j = 0; j < 16; ++j) {
                o += (float)((w >> (2 * j)) & 1u) * E[j];
                o += (float)((w >> (2 * j + 1)) & 1u) * O[j];
            }
            o *= zs[p_l * 16 + i];
            float l = lbv;
            l = fmaf(w9[0], Wm0, l); l = fmaf(w9[1], Wm1, l); l = fmaf(w9[2], Wm2, l);
            l = fmaf(w9[3], Wc0, l); l = fmaf(w9[4], Wc1, l); l = fmaf(w9[5], Wc2, l);
            l = fmaf(w9[6], Wp0, l); l = fmaf(w9[7], Wp1, l); l = fmaf(w9[8], Wp2, l);
            out[((b * 1024 + n) << 8) + c] = o + l;
            Wm0 = Wc0; Wm1 = Wc1; Wm2 = Wc2;
            Wc0 = Wp0; Wc1 = Wp1; Wc2 = Wp2;
        }
    }
}

extern "C" void kernel_launch(void* const* d_in, const int* in_sizes, int n_in,
                              void* d_out, int out_size, void* d_ws, size_t ws_size,
                              hipStream_t stream)
{
    const float* x     = (const float*)d_in[0];
    const float* Wqk   = (const float*)d_in[1];
    const float* bqk   = (const float*)d_in[2];
    const float* gamma = (const float*)d_in[3];
    const float* beta  = (const float*)d_in[4];
    const float* lw    = (const float*)d_in[5];
    const float* lb    = (const float*)d_in[6];
    float* out = (float*)d_out;
    unsigned* ws = (unsigned*)d_ws;
    unsigned* mq = ws + WS_MQ;
    unsigned* mk = ws + WS_MK;
    float* tbl  = (float*)(ws + WS_TBL);
    float* kvp  = (float*)(ws + WS_KVP);
    float* kmp  = (float*)(ws + WS_KMP);

    hipLaunchKernelGGL(phaseA_kernel, dim3(1408), dim3(512), 0, stream,
                       x, Wqk, bqk, gamma, beta, mq, mk, out + OFF_VIMG, tbl);
    hipLaunchKernelGGL(phaseB_kernel, dim3(256), dim3(512), 0, stream,
                       x, Wqk, bqk, gamma, beta, mq, mk, tbl, kvp, kmp);
    hipLaunchKernelGGL(phaseC_kernel, dim3(2560), dim3(256), 0, stream,
                       mq, mk, x, tbl, kvp, kmp, lw, lb, out);
}

// Round 10
// 95.061 us; speedup vs baseline: 2.0869x; 2.0869x over previous
//
#include <hip/hip_runtime.h>
#include <cstdint>
#include <cstddef>

// Outputs concat (f32): out(8,1024,256) qh(8,8,1024,32) kh(8,8,1024,32)
//                       v_img(8,256,32,32) atten(8,8,1024,1024)
#define OFF_OUT   0
#define OFF_QH    2097152
#define OFF_KH    4194304
#define OFF_VIMG  6291456
#define OFF_ATT   8388608

// ws layout (4-byte units)
#define WS_MQ   0        // 8*8*1024 u32
#define WS_MK   65536
#define WS_TBL  131072   // 1024*128*2 f32 (cos,sin interleaved)
#define WS_KVP  393216   // 64 bh * 4 seg * 32*32 f32 partial kv
#define WS_KMP  655360   // 64 bh * 4 seg * 32 f32 partial k-bit counts

typedef float f32x4 __attribute__((ext_vector_type(4)));

// W LDS group layout: group g (8 floats) at 8g + 4*(g>>2); row stride 140.
// Non-overlapping (max 139), 16B-aligned, 2 addresses/bank per wave read.
__device__ __forceinline__ int wcol(int g) { return g * 8 + 4 * (g >> 2); }

// ---- fused GEMM+BN+LIF+pack; 256 thr; tile 8n x 8b x 128c; thread 8b x 8c ----
// k-split: 2 groups of 128 thr (ks = t>>7) over K-halves, combined via LDS.
// pool: W[ks][32][140] at [0,8960); x[ks][32][68] at [8960,13312)
// post: comb[64][129] at [0,8256); nib bytes at (uchar*)(pool+8960)
__device__ __forceinline__ void gemm_lif_256(
    const float* __restrict__ x, const float* __restrict__ Wqk,
    const float* __restrict__ bqk, const float* __restrict__ gamma,
    const float* __restrict__ beta, unsigned* __restrict__ mq,
    unsigned* __restrict__ mk, float* pool,
    int blk_n, int blk_c, int t)
{
    const int ks = t >> 7, tl = t & 127;
    const int c_t = tl & 15, n_l = tl >> 4;
    const int n0 = blk_n * 8, c0 = blk_c * 128;
    float* wpool = pool + ks * 4480;            // [32][140]
    float* xpool = pool + 8960 + ks * 2176;     // [32][68]

    float acc[8][8];
    #pragma unroll
    for (int b = 0; b < 8; ++b)
        #pragma unroll
        for (int j = 0; j < 8; ++j) acc[b][j] = 0.f;

    // x staging: 4 tasks; LDS column m = um + 16*i <-> (b = m&7, nl = m>>3).
    // global row for task i: nl = (um>>3) + 2*i  ->  offset i*2*256.
    const int um = tl >> 3, ukq = tl & 7;
    const float* gx0 = x + ((size_t)(um & 7) * 1024 + n0 + (um >> 3)) * 256
                         + ks * 128 + ukq * 4;
    // W staging: 8 tasks; rows kk = (tl>>5) + 4*i; cols c4 = (tl&31)*4.
    const float* gw0 = Wqk + (size_t)(ks * 128 + (tl >> 5)) * 512 + c0 + (tl & 31) * 4;
    const int wg = (tl & 31) >> 1;
    float* lw_ = wpool + (tl >> 5) * 140 + wcol(wg) + (tl & 1) * 4;
    float* lx_ = xpool + (ukq * 4) * 68 + um;

    f32x4 px[4], pw[8];
    #pragma unroll
    for (int i = 0; i < 4; ++i) px[i] = *(const f32x4*)(gx0 + (size_t)(i * 2) * 256);
    #pragma unroll
    for (int i = 0; i < 8; ++i) pw[i] = *(const f32x4*)(gw0 + (size_t)(i * 4) * 512);

    for (int p = 0; p < 4; ++p) {
        #pragma unroll
        for (int i = 0; i < 4; ++i)
            #pragma unroll
            for (int j = 0; j < 4; ++j)
                lx_[j * 68 + i * 16] = px[i][j];
        #pragma unroll
        for (int i = 0; i < 8; ++i)
            *(f32x4*)(lw_ + i * 4 * 140) = pw[i];
        __syncthreads();
        if (p < 3) {
            int ko = (p + 1) * 32;
            #pragma unroll
            for (int i = 0; i < 4; ++i)
                px[i] = *(const f32x4*)(gx0 + (size_t)(i * 2) * 256 + ko);
            #pragma unroll
            for (int i = 0; i < 8; ++i)
                pw[i] = *(const f32x4*)(gw0 + (size_t)(ko + i * 4) * 512);
        }
        const int xc = n_l * 8;
        const int wc = wcol(c_t);
        #pragma unroll 8
        for (int kk = 0; kk < 32; ++kk) {
            f32x4 xa = *(const f32x4*)(xpool + kk * 68 + xc);
            f32x4 xb = *(const f32x4*)(xpool + kk * 68 + xc + 4);
            f32x4 wa = *(const f32x4*)(wpool + kk * 140 + wc);
            f32x4 wb = *(const f32x4*)(wpool + kk * 140 + wc + 4);
            #pragma unroll
            for (int b = 0; b < 4; ++b) {
                #pragma unroll
                for (int j = 0; j < 4; ++j) {
                    acc[b][j]         = fmaf(xa[b], wa[j], acc[b][j]);
                    acc[b][j + 4]     = fmaf(xa[b], wb[j], acc[b][j + 4]);
                    acc[b + 4][j]     = fmaf(xb[b], wa[j], acc[b + 4][j]);
                    acc[b + 4][j + 4] = fmaf(xb[b], wb[j], acc[b + 4][j + 4]);
                }
            }
        }
        __syncthreads();
    }

    // combine k-halves: comb[idx][tl], idx = b*8+j, rows padded to 129
    float* comb = pool;
    if (ks == 1) {
        #pragma unroll
        for (int b = 0; b < 8; ++b)
            #pragma unroll
            for (int j = 0; j < 8; ++j)
                comb[(b * 8 + j) * 129 + tl] = acc[b][j];
    }
    __syncthreads();
    unsigned char* nib = (unsigned char*)(pool + 8960);   // [8 nl][16 c_t][8 b]
    if (ks == 0) {
        #pragma unroll
        for (int b = 0; b < 8; ++b)
            #pragma unroll
            for (int j = 0; j < 8; ++j)
                acc[b][j] += comb[(b * 8 + j) * 129 + tl];
        float g = gamma[n0 + n_l], be = beta[n0 + n_l];
        f32x4 bqa = *(const f32x4*)(bqk + c0 + c_t * 8);
        f32x4 bqb = *(const f32x4*)(bqk + c0 + c_t * 8 + 4);
        float v[8];
        #pragma unroll
        for (int j = 0; j < 8; ++j) v[j] = 0.f;
        #pragma unroll
        for (int b = 0; b < 8; ++b) {
            unsigned byte = 0;
            #pragma unroll
            for (int j = 0; j < 8; ++j) {
                float bqv = (j < 4) ? bqa[j] : bqb[j - 4];
                float a = (acc[b][j] + bqv) * g + be;
                v[j] = v[j] + (a - v[j]) * 0.5f;
                bool sp = (v[j] >= 1.f);
                v[j] = sp ? 0.f : v[j];
                byte |= (sp ? 1u : 0u) << j;
            }
            nib[n_l * 128 + c_t * 8 + b] = (unsigned char)byte;
        }
    }
    __syncthreads();
    // word assembly: t -> (b = t&7, w = (t>>3)&3, nl = t>>5)
    {
        int b = t & 7, w = (t >> 3) & 3, nl = t >> 5;
        unsigned wd = 0;
        #pragma unroll
        for (int j = 0; j < 4; ++j)
            wd |= (unsigned)nib[nl * 128 + (w * 4 + j) * 8 + b] << (8 * j);
        unsigned h = (unsigned)((blk_c & 1) * 4 + w);
        unsigned* dst = (blk_c < 2) ? mq : mk;
        dst[b * 8192 + h * 1024 + n0 + nl] = wd;
    }
}

// =====================================================================
// Phase A (256 thr, 2816 blocks):
//  [0,256)     : GEMM blk_c in {2,3} -> mk
//  [256,2304)  : vimg transpose
//  [2304,2816) : rope table
// =====================================================================
__global__ __launch_bounds__(256) void phaseA_kernel(
    const float* __restrict__ x, const float* __restrict__ Wqk,
    const float* __restrict__ bqk, const float* __restrict__ gamma,
    const float* __restrict__ beta, unsigned* __restrict__ mq,
    unsigned* __restrict__ mk, float* __restrict__ vimg,
    float* __restrict__ tbl)
{
    __shared__ float smem[13312];
    int t = threadIdx.x;
    int blk = blockIdx.x;
    if (blk < 256) {
        gemm_lif_256(x, Wqk, bqk, gamma, beta, mq, mk, smem,
                     blk >> 1, 2 + (blk & 1), t);
        return;
    }
    if (blk >= 2304) {                     // ---- rope table ----
        int id = (blk - 2304) * 256 + t;   // 131072 total
        int j = id & 127, n = id >> 7;
        int i = (j < 64) ? j : j - 64;
        float th = powf(10000.0f, -(float)i * (1.0f / 64.0f));
        float pos = (float)((j < 64) ? (n >> 5) : (n & 31));
        float ang = pos * th;
        tbl[n * 256 + j * 2]     = cosf(ang);
        tbl[n * 256 + j * 2 + 1] = sinf(ang);
        return;
    }
    // ---- vimg transpose ----
    float* s = smem;                       // [32][33]
    int tile = blk - 256;
    int b = tile >> 8, ti = tile & 255;
    int p0 = (ti >> 3) * 32, c0 = (ti & 7) * 32;
    int row = t >> 3, c4 = (t & 7) * 4;
    const float4 vl = *(const float4*)&x[(b * 1024 + p0 + row) * 256 + c0 + c4];
    s[row * 33 + c4 + 0] = vl.x; s[row * 33 + c4 + 1] = vl.y;
    s[row * 33 + c4 + 2] = vl.z; s[row * 33 + c4 + 3] = vl.w;
    __syncthreads();
    int cc = t >> 3, p4 = (t & 7) * 4;
    f32x4 o;
    o.x = s[(p4 + 0) * 33 + cc]; o.y = s[(p4 + 1) * 33 + cc];
    o.z = s[(p4 + 2) * 33 + cc]; o.w = s[(p4 + 3) * 33 + cc];
    *(f32x4*)&vimg[(b * 256 + c0 + cc) * 1024 + p0 + p4] = o;
}

// =====================================================================
// Phase B (256 thr, 512 blocks):
//  [0,256)   : GEMM blk_c in {0,1} -> mq
//  [256,512) : kv partials + k-bit counts (needs mk, tbl)
// =====================================================================
__global__ __launch_bounds__(256) void phaseB_kernel(
    const float* __restrict__ x, const float* __restrict__ Wqk,
    const float* __restrict__ bqk, const float* __restrict__ gamma,
    const float* __restrict__ beta, unsigned* __restrict__ mq,
    unsigned* __restrict__ mk, const float* __restrict__ tbl,
    float* __restrict__ kvp, float* __restrict__ kmp)
{
    __shared__ float smem[13312];
    int t = threadIdx.x;
    int blk = blockIdx.x;
    if (blk < 256) {
        gemm_lif_256(x, Wqk, bqk, gamma, beta, mq, mk, smem,
                     blk >> 1, blk & 1, t);
        return;
    }
    // ---- kv partials ----
    int unit = blk - 256;                  // 0..255
    int bh = unit >> 2, seg = unit & 3;
    int b = bh >> 3, h = bh & 7;
    int n0 = seg * 256;
    float* kr   = smem;                    // [64][36]
    float* vhs  = smem + 2304;             // [64][33]
    float* part = smem + 4416;             // [8][32]
    int d = t & 31, ch = t >> 5;
    int sc = 0;
    for (int i = 0; i < 32; ++i)
        sc += (mk[bh * 1024 + n0 + ch * 32 + i] >> d) & 1u;
    part[ch * 32 + d] = (float)sc;
    __syncthreads();
    if (t < 32) {
        float cs = 0.f;
        #pragma unroll
        for (int j = 0; j < 8; ++j) cs += part[j * 32 + t];
        kmp[bh * 128 + seg * 32 + t] = cs;
    }
    float a0 = 0, a1 = 0, a2 = 0, a3 = 0;
    int e = t & 31, db = (t >> 5) * 4;
    for (int c0 = n0; c0 < n0 + 256; c0 += 64) {
        __syncthreads();
        #pragma unroll
        for (int i = 0; i < 8; ++i) {
            int f = t + i * 256;
            int nn = f >> 5, dd = f & 31;
            int n = c0 + nn;
            unsigned w = mk[bh * 1024 + n];
            float kd = 1.0f + (float)((w >> dd) & 1u);
            float ko = 1.0f + (float)((w >> (dd ^ 1)) & 1u);
            const float* cp = tbl + n * 256 + h * 32 + (dd & ~1);
            float cc2 = cp[0], ss2 = cp[1];
            kr[nn * 36 + dd] = (dd & 1) ? (ss2 * ko + cc2 * kd) : (cc2 * kd - ss2 * ko);
            vhs[nn * 33 + dd] = x[(b * 1024 + n) * 256 + h * 32 + dd];
        }
        __syncthreads();
        #pragma unroll 8
        for (int nn = 0; nn < 64; ++nn) {
            float ve = vhs[nn * 33 + e];
            float4 kk = *(const float4*)&kr[nn * 36 + db];
            a0 = fmaf(kk.x, ve, a0); a1 = fmaf(kk.y, ve, a1);
            a2 = fmaf(kk.z, ve, a2); a3 = fmaf(kk.w, ve, a3);
        }
    }
    float* dst = kvp + bh * 4096 + seg * 1024;
    dst[(db + 0) * 32 + e] = a0;
    dst[(db + 1) * 32 + e] = a1;
    dst[(db + 2) * 32 + e] = a2;
    dst[(db + 3) * 32 + e] = a3;
}

// =====================================================================
// Phase C (256 thr, 2560 blocks): all heavy writes (plain stores)
//  [0,512)    : out = q_rope@kv * z + lepe
//  [512,2560) : atten + qh/kh regen
// =====================================================================
__global__ __launch_bounds__(256) void phaseC_kernel(
    const unsigned* __restrict__ mq, const unsigned* __restrict__ mk,
    const float* __restrict__ x, const float* __restrict__ tbl,
    const float* __restrict__ kvp, const float* __restrict__ kmp,
    const float* __restrict__ lw, const float* __restrict__ lb,
    float* __restrict__ outbase)
{
    int t = threadIdx.x;
    if (blockIdx.x >= 512) {               // ---- atten + qh/kh ----
        int blk = blockIdx.x - 512;
        int bh = blk >> 5;
        int tile = blk & 31;
        float* qh = outbase + OFF_QH;
        float* kh = outbase + OFF_KH;
        float* att = outbase + OFF_ATT;
        {
            int row = tile * 32 + (t >> 3);
            int d0 = (t & 7) * 4;
            unsigned wq = mq[bh * 1024 + row], wk = mk[bh * 1024 + row];
            f32x4 a, bb;
            a.x = 1.f + (float)((wq >> (d0 + 0)) & 1u);
            a.y = 1.f + (float)((wq >> (d0 + 1)) & 1u);
            a.z = 1.f + (float)((wq >> (d0 + 2)) & 1u);
            a.w = 1.f + (float)((wq >> (d0 + 3)) & 1u);
            bb.x = 1.f + (float)((wk >> (d0 + 0)) & 1u);
            bb.y = 1.f + (float)((wk >> (d0 + 1)) & 1u);
            bb.z = 1.f + (float)((wk >> (d0 + 2)) & 1u);
            bb.w = 1.f + (float)((wk >> (d0 + 3)) & 1u);
            *(f32x4*)&qh[((bh * 1024 + row) << 5) + d0] = a;
            *(f32x4*)&kh[((bh * 1024 + row) << 5) + d0] = bb;
        }
        uint4 mm = ((const uint4*)(mk + bh * 1024))[t];
        float4 rr;
        rr.x = (float)__popc(mm.x); rr.y = (float)__popc(mm.y);
        rr.z = (float)__popc(mm.z); rr.w = (float)__popc(mm.w);
        float* base = att + ((size_t)bh * 1024 + (size_t)tile * 32) * 1024;
        const unsigned* mqrow = mq + bh * 1024 + tile * 32;
        for (int row = 0; row < 32; ++row) {
            unsigned mqw = mqrow[row];
            float rq = 32.0f + (float)__popc(mqw);
            f32x4 o;
            o.x = rq + rr.x + (float)__popc(mqw & mm.x);
            o.y = rq + rr.y + (float)__popc(mqw & mm.y);
            o.z = rq + rr.z + (float)__popc(mqw & mm.z);
            o.w = rq + rr.w + (float)__popc(mqw & mm.w);
            ((f32x4*)(base + (size_t)row * 1024))[t] = o;
        }
        return;
    }
    // ---- out ----
    int bi = blockIdx.x;
    int bh = bi >> 3, sub = bi & 7;
    int pseg = sub >> 1, half = sub & 1;
    int b = bh >> 3, h = bh & 7;
    bool hy = (h < 4);
    int e = t & 31, p_l = t >> 5;
    int p = pseg * 8 + p_l;
    int q0 = half * 16;
    float* out = outbase + OFF_OUT;

    __shared__ float kvs[32][32];
    __shared__ float kmf[32];
    __shared__ float zs[128];
    const float inv = 1.0f / 1024.0f;
    #pragma unroll
    for (int i = 0; i < 4; ++i) {
        int f = t + i * 256;
        const float* kp = kvp + bh * 4096 + f;
        kvs[f >> 5][f & 31] = (kp[0] + kp[1024] + kp[2048] + kp[3072]) * inv;
    }
    if (t < 32) {
        const float* mp = kmp + bh * 128 + t;
        kmf[t] = 1.0f + (mp[0] + mp[32] + mp[64] + mp[96]) * inv;
    }
    __syncthreads();
    float S = 0.f;
    #pragma unroll
    for (int dd = 0; dd < 32; ++dd) S += kmf[dd];
    if (t < 128) {
        int pl2 = t >> 4, iq = t & 15;
        int pp = pseg * 8 + pl2, qq = q0 + iq;
        int n = hy ? (pp * 32 + qq) : (qq * 32 + pp);
        unsigned w = mq[bh * 1024 + n];
        float acc = S;
        #pragma unroll
        for (int dd = 0; dd < 32; ++dd)
            acc += (float)((w >> dd) & 1u) * kmf[dd];
        zs[t] = 1.0f / (acc + 1e-6f);
    }
    int n_ref = hy ? (p * 32) : p;
    const float* cp = tbl + n_ref * 256 + h * 32;
    float E[16], O[16], B = 0.f;
    #pragma unroll
    for (int j = 0; j < 16; ++j) {
        float c2 = cp[2 * j], s2 = cp[2 * j + 1];
        float K0 = kvs[2 * j][e], K1 = kvs[2 * j + 1][e];
        E[j] = c2 * K0 + s2 * K1;
        O[j] = c2 * K1 - s2 * K0;
        B += E[j] + O[j];
    }
    __syncthreads();
    int c = h * 32 + e;
    float w9[9];
    #pragma unroll
    for (int j = 0; j < 9; ++j) w9[j] = lw[c * 9 + j];
    float lbv = lb[c];
    const float* xb = x + (size_t)b * 262144 + c;
    auto ld = [&](int yy, int xx) -> float {
        if ((unsigned)yy > 31u || (unsigned)xx > 31u) return 0.f;
        return xb[(yy * 32 + xx) * 256];
    };
    if (hy) {
        int y = p;
        float Wm0 = ld(y - 1, q0 - 1), Wm1 = ld(y, q0 - 1), Wm2 = ld(y + 1, q0 - 1);
        float Wc0 = ld(y - 1, q0),     Wc1 = ld(y, q0),     Wc2 = ld(y + 1, q0);
        #pragma unroll 4
        for (int i = 0; i < 16; ++i) {
            int m = q0 + i;
            float Wp0 = ld(y - 1, m + 1), Wp1 = ld(y, m + 1), Wp2 = ld(y + 1, m + 1);
            int n = y * 32 + m;
            unsigned w = mq[bh * 1024 + n];
            float o = B;
            #pragma unroll
            for (int j = 0; j < 16; ++j) {
                o += (float)((w >> (2 * j)) & 1u) * E[j];
                o += (float)((w >> (2 * j + 1)) & 1u) * O[j];
            }
            o *= zs[p_l * 16 + i];
            float l = lbv;
            l = fmaf(w9[0], Wm0, l); l = fmaf(w9[1], Wc0, l); l = fmaf(w9[2], Wp0, l);
            l = fmaf(w9[3], Wm1, l); l = fmaf(w9[4], Wc1, l); l = fmaf(w9[5], Wp1, l);
            l = fmaf(w9[6], Wm2, l); l = fmaf(w9[7], Wc2, l); l = fmaf(w9[8], Wp2, l);
            out[((b * 1024 + n) << 8) + c] = o + l;
            Wm0 = Wc0; Wm1 = Wc1; Wm2 = Wc2;
            Wc0 = Wp0; Wc1 = Wp1; Wc2 = Wp2;
        }
    } else {
        int xx0 = p;
        float Wm0 = ld(q0 - 1, xx0 - 1), Wm1 = ld(q0 - 1, xx0), Wm2 = ld(q0 - 1, xx0 + 1);
        float Wc0 = ld(q0, xx0 - 1),     Wc1 = ld(q0, xx0),     Wc2 = ld(q0, xx0 + 1);
        #pragma unroll 4
        for (int i = 0; i < 16; ++i) {
            int m = q0 + i;
            float Wp0 = ld(m + 1, xx0 - 1), Wp1 = ld(m + 1, xx0), Wp2 = ld(m + 1, xx0 + 1);
            int n = m * 32 + xx0;
            unsigned w = mq[bh * 1024 + n];
            float o = B;
            #pragma unroll
            for (int j = 0; j < 16; ++j) {
                o += (float)((w >> (2 * j)) & 1u) * E[j];
                o += (float)((w >> (2 * j + 1)) & 1u) * O[j];
            }
            o *= zs[p_l * 16 + i];
            float l = lbv;
            l = fmaf(w9[0], Wm0, l); l = fmaf(w9[1], Wm1, l); l = fmaf(w9[2], Wm2, l);
            l = fmaf(w9[3], Wc0, l); l = fmaf(w9[4], Wc1, l); l = fmaf(w9[5], Wc2, l);
            l = fmaf(w9[6], Wp0, l); l = fmaf(w9[7], Wp1, l); l = fmaf(w9[8], Wp2, l);
            out[((b * 1024 + n) << 8) + c] = o + l;
            Wm0 = Wc0; Wm1 = Wc1; Wm2 = Wc2;
            Wc0 = Wp0; Wc1 = Wp1; Wc2 = Wp2;
        }
    }
}

extern "C" void kernel_launch(void* const* d_in, const int* in_sizes, int n_in,
                              void* d_out, int out_size, void* d_ws, size_t ws_size,
                              hipStream_t stream)
{
    const float* x     = (const float*)d_in[0];
    const float* Wqk   = (const float*)d_in[1];
    const float* bqk   = (const float*)d_in[2];
    const float* gamma = (const float*)d_in[3];
    const float* beta  = (const float*)d_in[4];
    const float* lw    = (const float*)d_in[5];
    const float* lb    = (const float*)d_in[6];
    float* out = (float*)d_out;
    unsigned* ws = (unsigned*)d_ws;
    unsigned* mq = ws + WS_MQ;
    unsigned* mk = ws + WS_MK;
    float* tbl  = (float*)(ws + WS_TBL);
    float* kvp  = (float*)(ws + WS_KVP);
    float* kmp  = (float*)(ws + WS_KMP);

    hipLaunchKernelGGL(phaseA_kernel, dim3(2816), dim3(256), 0, stream,
                       x, Wqk, bqk, gamma, beta, mq, mk, out + OFF_VIMG, tbl);
    hipLaunchKernelGGL(phaseB_kernel, dim3(512), dim3(256), 0, stream,
                       x, Wqk, bqk, gamma, beta, mq, mk, tbl, kvp, kmp);
    hipLaunchKernelGGL(phaseC_kernel, dim3(2560), dim3(256), 0, stream,
                       mq, mk, x, tbl, kvp, kmp, lw, lb, out);
}